// Round 20
// baseline (160.429 us; speedup 1.0000x reference)
//
#include <hip/hip_runtime.h>
#include <math.h>

#define Bb 128
#define Tt 1024
#define Ll 96
#define NSEG 16
#define DELTA 16
#define CUT(s) (1 + ((Tt - 1) * (s)) / NSEG)

// ws per batch: [0..N) end_sum (f32); [N..2N) junc_sum; [2N..3N) end_dk (i32);
// [3N..4N) junc_dk; [4N] ps.
#define WS_STRIDE 80

typedef float v2f __attribute__((ext_vector_type(2)));
typedef int   v2i __attribute__((ext_vector_type(2)));

// Cross-group (lane ^ 32) sum via v_permlane32_swap (VALU pipe, not LDS).
static __device__ __forceinline__ float xadd32(float p) {
#if __has_builtin(__builtin_amdgcn_permlane32_swap)
    v2i rr = __builtin_amdgcn_permlane32_swap(__float_as_int(p),
                                              __float_as_int(p), false, false);
    return __int_as_float(rr.x) + __int_as_float(rr.y);
#else
    return p + __shfl_xor(p, 32, 64);
#endif
}

// guaranteed packed fp32 math (VOP3P); operands are 64-bit VGPR pairs.
#define PKFMA(d, a, b) asm("v_pk_fma_f32 %0, %1, %2, %0" : "+v"(d) : "v"(a), "v"(b));
#define PKMUL(d, a, b) asm("v_pk_mul_f32 %0, %1, %2"     : "=v"(d) : "v"(a), "v"(b));

// FORWARD-ONLY overlapped chains (R16/R19 scheme; round-20 = instruction diet).
// R19 accounting: throughput saturates at ~9.4 steps/us/CU with VALUBusy 57%
// and DS ~6% -> issued VALU ~290/step vs ~140 in source: compiler overhead
// (scalarized v2f FMA, pair-repack movs, queue shifts). This round deletes it:
//  1. ds_read_b64 pairs (clean v2f FMA operands, no repack)
//  2. inline-asm v_pk_fma_f32 / v_pk_mul_f32 (packed guaranteed; mul-first
//     kills the 12 acc-init movs)
//  3. k via readfirstlane(Q0.x) (lane 0 holds state[0]) -> SALU bookkeeping,
//     no separate Pk LDS read
//  4. unroll-6 static queue rotation (kills 15 shift movs/step); <=5-step
//     no-refill tail
// All changes bit-identical: absmax must remain 0.0.
__global__ __launch_bounds__(64, 1)
void crf_scan_kernel(
    const float* __restrict__ inputs,      // (B, T, L) fp32
    const int*   __restrict__ labels_idx,  // (B, T) int32
    const float* __restrict__ trans,       // (L, L) fp32
    float*       __restrict__ ws)          // 128 x WS_STRIDE floats
{
    const int cid = blockIdx.x / Bb;       // 0..NSEG-1 chains, NSEG = scores
    const int b   = blockIdx.x % Bb;
    const int i   = threadIdx.x;           // 0..63

    const float* xbase = inputs + (size_t)b * Tt * Ll;
    float* wsb = ws + (size_t)b * WS_STRIDE;
    int*   wsi = reinterpret_cast<int*>(wsb);

    if (cid == NSEG) {
        // ================= SCORES =================
        float ps = 0.f;
        const int* lb = labels_idx + b * Tt;
        #pragma unroll 4
        for (int t = i; t < Tt; t += 64) {
            int i0 = lb[t];
            ps += xbase[t * Ll + i0];
            if (t < Tt - 1) ps += trans[i0 * Ll + lb[t + 1]];
        }
        #pragma unroll
        for (int off = 32; off; off >>= 1) ps += __shfl_xor(ps, off, 64);
        if (i == 0) wsb[4 * NSEG] = ps;
        return;
    }

    const int s  = cid + 1;                          // 1..NSEG
    const int lo = CUT(s - 1), hi = CUT(s);          // segment [lo, hi)
    const int w0 = (s == 1) ? 1 : ((lo - DELTA < 1) ? 1 : lo - DELTA);
    const int jt = (s == 1) ? 0 : (lo - 1);          // junction t (0 = never)

    const int g   = i >> 5;            // group: state half [48g, 48g+48)
    const int j   = i & 31;            // slot: owns cols j, j+32, j+64
    const int g48 = g * 48;
    const int cA  = j, cB = j + 32, cC = j + 64;

    __shared__ __align__(16) float buf[Ll];

#define EP24(X) \
    X(0)  X(1)  X(2)  X(3)  X(4)  X(5)  X(6)  X(7)  X(8)  X(9)  X(10) X(11) \
    X(12) X(13) X(14) X(15) X(16) X(17) X(18) X(19) X(20) X(21) X(22) X(23)

#define EDECL(p) v2f EA##p, EB##p, EC##p;
    EP24(EDECL)
#undef EDECL
    // fwd layout: EA_p = {E[2p'][cA], E[2p'+1][cA]} for own-half elems
#define EINIT(p) { \
        int e0 = (g48 + 2*(p)) * Ll, e1 = (g48 + 2*(p) + 1) * Ll; \
        EA##p = (v2f){__expf(trans[e0 + cA]), __expf(trans[e1 + cA])}; \
        EB##p = (v2f){__expf(trans[e0 + cB]), __expf(trans[e1 + cB])}; \
        EC##p = (v2f){__expf(trans[e0 + cC]), __expf(trans[e1 + cC])}; \
        asm volatile("" ::: "memory"); }
    EP24(EINIT)
#undef EINIT

    // 24 x ds_read_b64: pair p = state elems {48g+2p, 48g+2p+1}, a clean v2f.
#define QDECL(p) v2f Q##p;
    EP24(QDECL)
#undef QDECL
#define PRELOAD { const v2f* qb_ = reinterpret_cast<const v2f*>(buf) + g * 24; \
        Q0  = qb_[0];  Q1  = qb_[1];  Q2  = qb_[2];  Q3  = qb_[3];  \
        Q4  = qb_[4];  Q5  = qb_[5];  Q6  = qb_[6];  Q7  = qb_[7];  \
        Q8  = qb_[8];  Q9  = qb_[9];  Q10 = qb_[10]; Q11 = qb_[11]; \
        Q12 = qb_[12]; Q13 = qb_[13]; Q14 = qb_[14]; Q15 = qb_[15]; \
        Q16 = qb_[16]; Q17 = qb_[17]; Q18 = qb_[18]; Q19 = qb_[19]; \
        Q20 = qb_[20]; Q21 = qb_[21]; Q22 = qb_[22]; Q23 = qb_[23]; }

    // matvec: pair p feeds EA_p/EB_p/EC_p; mul-first on p=0,1 (no acc init).
#define MATVEC \
        v2f aA0, aA1, aB0, aB1, aC0, aC1; \
        PKMUL(aA0, Q0, EA0)  PKMUL(aB0, Q0, EB0)  PKMUL(aC0, Q0, EC0) \
        PKMUL(aA1, Q1, EA1)  PKMUL(aB1, Q1, EB1)  PKMUL(aC1, Q1, EC1) \
        PKFMA(aA0, Q2, EA2)  PKFMA(aB0, Q2, EB2)  PKFMA(aC0, Q2, EC2) \
        PKFMA(aA1, Q3, EA3)  PKFMA(aB1, Q3, EB3)  PKFMA(aC1, Q3, EC3) \
        PKFMA(aA0, Q4, EA4)  PKFMA(aB0, Q4, EB4)  PKFMA(aC0, Q4, EC4) \
        PKFMA(aA1, Q5, EA5)  PKFMA(aB1, Q5, EB5)  PKFMA(aC1, Q5, EC5) \
        PKFMA(aA0, Q6, EA6)  PKFMA(aB0, Q6, EB6)  PKFMA(aC0, Q6, EC6) \
        PKFMA(aA1, Q7, EA7)  PKFMA(aB1, Q7, EB7)  PKFMA(aC1, Q7, EC7) \
        PKFMA(aA0, Q8, EA8)  PKFMA(aB0, Q8, EB8)  PKFMA(aC0, Q8, EC8) \
        PKFMA(aA1, Q9, EA9)  PKFMA(aB1, Q9, EB9)  PKFMA(aC1, Q9, EC9) \
        PKFMA(aA0, Q10, EA10) PKFMA(aB0, Q10, EB10) PKFMA(aC0, Q10, EC10) \
        PKFMA(aA1, Q11, EA11) PKFMA(aB1, Q11, EB11) PKFMA(aC1, Q11, EC11) \
        PKFMA(aA0, Q12, EA12) PKFMA(aB0, Q12, EB12) PKFMA(aC0, Q12, EC12) \
        PKFMA(aA1, Q13, EA13) PKFMA(aB1, Q13, EB13) PKFMA(aC1, Q13, EC13) \
        PKFMA(aA0, Q14, EA14) PKFMA(aB0, Q14, EB14) PKFMA(aC0, Q14, EC14) \
        PKFMA(aA1, Q15, EA15) PKFMA(aB1, Q15, EB15) PKFMA(aC1, Q15, EC15) \
        PKFMA(aA0, Q16, EA16) PKFMA(aB0, Q16, EB16) PKFMA(aC0, Q16, EC16) \
        PKFMA(aA1, Q17, EA17) PKFMA(aB1, Q17, EB17) PKFMA(aC1, Q17, EC17) \
        PKFMA(aA0, Q18, EA18) PKFMA(aB0, Q18, EB18) PKFMA(aC0, Q18, EC18) \
        PKFMA(aA1, Q19, EA19) PKFMA(aB1, Q19, EB19) PKFMA(aC1, Q19, EC19) \
        PKFMA(aA0, Q20, EA20) PKFMA(aB0, Q20, EB20) PKFMA(aC0, Q20, EC20) \
        PKFMA(aA1, Q21, EA21) PKFMA(aB1, Q21, EB21) PKFMA(aC1, Q21, EC21) \
        PKFMA(aA0, Q22, EA22) PKFMA(aB0, Q22, EB22) PKFMA(aC0, Q22, EC22) \
        PKFMA(aA1, Q23, EA23) PKFMA(aB1, Q23, EB23) PKFMA(aC1, Q23, EC23)

    float qA, qB, qC;
    int Dk = 0;
    float jsum = 1.f; int jdk = 0;
    int t = w0;

    // core step: k from lane 0's Q0.x (= state[0]) via readfirstlane (SALU).
#define STEP_CORE { \
        int kk_ = ((__builtin_amdgcn_readfirstlane(__float_as_int(Q0.x)) >> 23) & 0xff) - 127; \
        Dk += kk_; \
        float r_ = __uint_as_float((unsigned)(127 - kk_) << 23); \
        float wA_ = ewA * r_, wB_ = ewB * r_, wC_ = ewC * r_; \
        MATVEC \
        v2f tA_ = aA0 + aA1, tB_ = aB0 + aB1, tC_ = aC0 + aC1; \
        qA = xadd32(tA_.x + tA_.y) * wA_; \
        qB = xadd32(tB_.x + tB_.y) * wB_; \
        qC = xadd32(tC_.x + tC_.y) * wC_; \
        if (i < 32) { buf[cA] = qA; buf[cB] = qB; buf[cC] = qC; } \
        asm volatile("" ::: "memory"); \
        PRELOAD \
        if (t == jt) { \
            float ssum_ = qA + qB + qC; \
            ssum_ += __shfl_xor(ssum_, 16, 64); ssum_ += __shfl_xor(ssum_, 8, 64); \
            ssum_ += __shfl_xor(ssum_, 4, 64);  ssum_ += __shfl_xor(ssum_, 2, 64); \
            ssum_ += __shfl_xor(ssum_, 1, 64); \
            jsum = ssum_; jdk = Dk; } }

    // unrolled step: consume ew, refill ew from slot n, reload slot n (t+7).
#define STEP(n) { STEP_CORE \
        ewA = __expf(x##n##A); ewB = __expf(x##n##B); ewC = __expf(x##n##C); \
        int row_ = t + 7; if (row_ > Tt - 1) row_ = Tt - 1; \
        x##n##A = xbase[row_*Ll+cA]; x##n##B = xbase[row_*Ll+cB]; x##n##C = xbase[row_*Ll+cC]; \
        ++t; }

    // tail step (no refill): consume ew, refill ew from slot n.
#define STEPT(n) if (t < hi) { STEP_CORE \
        ewA = __expf(x##n##A); ewB = __expf(x##n##B); ewC = __expf(x##n##C); \
        ++t; }

    // ---- init state at t0 = w0-1: q = exp(x_{t0}) ----
    qA = __expf(xbase[(w0 - 1) * Ll + cA]);
    qB = __expf(xbase[(w0 - 1) * Ll + cB]);
    qC = __expf(xbase[(w0 - 1) * Ll + cC]);
    if (i < 32) { buf[cA] = qA; buf[cB] = qB; buf[cC] = qC; }
    asm volatile("" ::: "memory");
    PRELOAD

    // queue prologue: ew = exp(row w0); slots 0..5 = rows w0+1..w0+6
    float ewA = __expf(xbase[w0 * Ll + cA]);
    float ewB = __expf(xbase[w0 * Ll + cB]);
    float ewC = __expf(xbase[w0 * Ll + cC]);
#define ROWF(d) ((w0 + (d) > Tt - 1) ? (Tt - 1) : (w0 + (d)))
    float x0A = xbase[ROWF(1)*Ll+cA], x0B = xbase[ROWF(1)*Ll+cB], x0C = xbase[ROWF(1)*Ll+cC];
    float x1A = xbase[ROWF(2)*Ll+cA], x1B = xbase[ROWF(2)*Ll+cB], x1C = xbase[ROWF(2)*Ll+cC];
    float x2A = xbase[ROWF(3)*Ll+cA], x2B = xbase[ROWF(3)*Ll+cB], x2C = xbase[ROWF(3)*Ll+cC];
    float x3A = xbase[ROWF(4)*Ll+cA], x3B = xbase[ROWF(4)*Ll+cB], x3C = xbase[ROWF(4)*Ll+cC];
    float x4A = xbase[ROWF(5)*Ll+cA], x4B = xbase[ROWF(5)*Ll+cB], x4C = xbase[ROWF(5)*Ll+cC];
    float x5A = xbase[ROWF(6)*Ll+cA], x5B = xbase[ROWF(6)*Ll+cB], x5C = xbase[ROWF(6)*Ll+cC];
#undef ROWF

    // main loop: 6 steps per trip, static slot rotation (zero queue movs)
    while (t + 6 <= hi) {
        STEP(0) STEP(1) STEP(2) STEP(3) STEP(4) STEP(5)
    }
    // tail (<=5 steps, slots consumed in order, no refill needed)
    STEPT(0) STEPT(1) STEPT(2) STEPT(3) STEPT(4)

    // end capture at t = hi-1
    float esum = qA + qB + qC;
    #pragma unroll
    for (int off = 16; off; off >>= 1) esum += __shfl_xor(esum, off, 64);

    if (i == 0) {
        wsb[s - 1]            = esum;
        wsb[NSEG + s - 1]     = jsum;
        wsi[2 * NSEG + s - 1] = Dk;
        wsi[3 * NSEG + s - 1] = jdk;
    }
#undef STEP
#undef STEPT
#undef STEP_CORE
#undef PRELOAD
#undef MATVEC
#undef EP24
}

// logZ = sum_s [log(end_s) + ln2 DkEnd_s] - sum_{s>=2} [log(junc_s) + ln2 DkJunc_s]
__global__ __launch_bounds__(64, 1) void crf_combine_kernel(
    const float* __restrict__ ws, float* __restrict__ out)
{
    const int b = blockIdx.x;
    if (threadIdx.x != 0) return;
    const float* wsb = ws + (size_t)b * WS_STRIDE;
    const int*   wsi = reinterpret_cast<const int*>(wsb);
    const double LN2 = 0.6931471805599453;

    double acc = 0.0;
    #pragma unroll 1
    for (int s = 1; s <= NSEG; ++s) {
        acc += log((double)wsb[s - 1]) + LN2 * (double)wsi[2 * NSEG + s - 1];
        if (s >= 2)
            acc -= log((double)wsb[NSEG + s - 1]) + LN2 * (double)wsi[3 * NSEG + s - 1];
    }
    out[b] = (float)(acc - (double)wsb[4 * NSEG]);
}

extern "C" void kernel_launch(void* const* d_in, const int* in_sizes, int n_in,
                              void* d_out, int out_size, void* d_ws, size_t ws_size,
                              hipStream_t stream) {
    const float* inputs     = (const float*)d_in[0];
    const int*   labels_idx = (const int*)d_in[1];
    const float* trans      = (const float*)d_in[2];
    float*       out        = (float*)d_out;
    float*       ws         = (float*)d_ws;

    crf_scan_kernel<<<dim3((NSEG + 1) * Bb), dim3(64), 0, stream>>>(
        inputs, labels_idx, trans, ws);
    crf_combine_kernel<<<dim3(Bb), dim3(64), 0, stream>>>(ws, out);
}

// Round 21
// 136.102 us; speedup vs baseline: 1.1787x; 1.1787x over previous
//
#include <hip/hip_runtime.h>
#include <math.h>

#define Bb 128
#define Tt 1024
#define Ll 96
#define NSEG 16
#define DELTA 8
#define CUT(s) (1 + ((Tt - 1) * (s)) / NSEG)

// ws per batch: [0..N) end_sum (f32); [N..2N) junc_sum; [2N..3N) end_dk (i32);
// [3N..4N) junc_dk; [4N] ps.
#define WS_STRIDE 80

typedef float v2f __attribute__((ext_vector_type(2)));
typedef float v4f __attribute__((ext_vector_type(4)));
typedef int   v2i __attribute__((ext_vector_type(2)));

// Cross-group (lane ^ 32) sum via v_permlane32_swap (VALU pipe, not LDS).
static __device__ __forceinline__ float xadd32(float p) {
#if __has_builtin(__builtin_amdgcn_permlane32_swap)
    v2i rr = __builtin_amdgcn_permlane32_swap(__float_as_int(p),
                                              __float_as_int(p), false, false);
    return __int_as_float(rr.x) + __int_as_float(rr.y);
#else
    return p + __shfl_xor(p, 32, 64);
#endif
}

// FORWARD-ONLY overlapped chains (R16/R19 scheme, R19 source verbatim).
// Round-21 = single change DELTA 16 -> 8 (work 1263 -> 1143, 0.905x).
// Rationale: R20's instruction diet improved per-wave step time 0.90->0.63us
// but halved resident waves/CU (mechanism not isolable from counters) for a
// net loss; R19 is the best verified config at 0.0535us/step, and throughput
// is work-proportional across R14/15/16/19 (0.050-0.054us/step at 4.5-15.5
// waves/CU). Junction error ~kappa^8 <= 6.5e-4 x15 junctions ~ <=5e-3 in
// logZ - absmax may legitimately move off 0.0, staying ~3 orders below tol.
//   logZ telescope: chain s warms up DELTA steps before its segment from
//   y=exp(x_{w0-1}); Birkhoff contraction aligns direction; scale errors
//   telescope via scalars captured at junction (t=lo-1) and end (t=hi-1):
//   logZ = sum_s [log(end_s) + ln2 DkEnd_s]
//        - sum_{s>=2} [log(junc_s) + ln2 DkJunc_s]
__global__ __launch_bounds__(64, 1)
void crf_scan_kernel(
    const float* __restrict__ inputs,      // (B, T, L) fp32
    const int*   __restrict__ labels_idx,  // (B, T) int32
    const float* __restrict__ trans,       // (L, L) fp32
    float*       __restrict__ ws)          // 128 x WS_STRIDE floats
{
    const int cid = blockIdx.x / Bb;       // 0..NSEG-1 chains, NSEG = scores
    const int b   = blockIdx.x % Bb;
    const int i   = threadIdx.x;           // 0..63

    const float* xbase = inputs + (size_t)b * Tt * Ll;
    float* wsb = ws + (size_t)b * WS_STRIDE;
    int*   wsi = reinterpret_cast<int*>(wsb);

    if (cid == NSEG) {
        // ================= SCORES =================
        float ps = 0.f;
        const int* lb = labels_idx + b * Tt;
        #pragma unroll 4
        for (int t = i; t < Tt; t += 64) {
            int i0 = lb[t];
            ps += xbase[t * Ll + i0];
            if (t < Tt - 1) ps += trans[i0 * Ll + lb[t + 1]];
        }
        #pragma unroll
        for (int off = 32; off; off >>= 1) ps += __shfl_xor(ps, off, 64);
        if (i == 0) wsb[4 * NSEG] = ps;
        return;
    }

    const int s  = cid + 1;                          // 1..NSEG
    const int lo = CUT(s - 1), hi = CUT(s);          // segment [lo, hi)
    const int w0 = (s == 1) ? 1 : ((lo - DELTA < 1) ? 1 : lo - DELTA);
    const int jt = (s == 1) ? 0 : (lo - 1);          // junction t (0 = never)

    const int g   = i >> 5;            // group: state half [48g, 48g+48)
    const int j   = i & 31;            // slot: owns cols j, j+32, j+64
    const int g48 = g * 48;
    const int cA  = j, cB = j + 32, cC = j + 64;

    __shared__ __align__(16) float buf[Ll];

#define EP24(X) \
    X(0)  X(1)  X(2)  X(3)  X(4)  X(5)  X(6)  X(7)  X(8)  X(9)  X(10) X(11) \
    X(12) X(13) X(14) X(15) X(16) X(17) X(18) X(19) X(20) X(21) X(22) X(23)

#define EDECL(p) v2f EA##p, EB##p, EC##p;
    EP24(EDECL)
#undef EDECL
    // fwd layout: EA_p = {E[2p'][cA], E[2p'+1][cA]} for own-half elems
#define EINIT(p) { \
        int e0 = (g48 + 2*(p)) * Ll, e1 = (g48 + 2*(p) + 1) * Ll; \
        EA##p = (v2f){__expf(trans[e0 + cA]), __expf(trans[e1 + cA])}; \
        EB##p = (v2f){__expf(trans[e0 + cB]), __expf(trans[e1 + cB])}; \
        EC##p = (v2f){__expf(trans[e0 + cC]), __expf(trans[e1 + cC])}; \
        asm volatile("" ::: "memory"); }
    EP24(EINIT)
#undef EINIT

#define CHUNK(q, p0, p1) { \
        aA0 += (v2f){P##q.x, P##q.y} * EA##p0; \
        aA1 += (v2f){P##q.z, P##q.w} * EA##p1; \
        aB0 += (v2f){P##q.x, P##q.y} * EB##p0; \
        aB1 += (v2f){P##q.z, P##q.w} * EB##p1; \
        aC0 += (v2f){P##q.x, P##q.y} * EC##p0; \
        aC1 += (v2f){P##q.z, P##q.w} * EC##p1; }

#define MATVEC \
        CHUNK(0, 0, 1)   CHUNK(1, 2, 3)   CHUNK(2, 4, 5)   CHUNK(3, 6, 7)   \
        CHUNK(4, 8, 9)   CHUNK(5, 10,11)  CHUNK(6, 12,13)  CHUNK(7, 14,15)  \
        CHUNK(8, 16,17)  CHUNK(9, 18,19)  CHUNK(10,20,21)  CHUNK(11,22,23)

#define PRELOAD { const v4f* qb_ = reinterpret_cast<const v4f*>(buf) + g * 12; \
        P0 = qb_[0]; P1 = qb_[1]; P2  = qb_[2];  P3  = qb_[3];  \
        P4 = qb_[4]; P5 = qb_[5]; P6  = qb_[6];  P7  = qb_[7];  \
        P8 = qb_[8]; P9 = qb_[9]; P10 = qb_[10]; P11 = qb_[11]; \
        Pk = buf[0]; }

    v4f P0,P1,P2,P3,P4,P5,P6,P7,P8,P9,P10,P11;
    float Pk;

    // init state at t0 = w0-1: q = exp(x_{t0}) (exact for s=1; warmup seed)
    float qA = __expf(xbase[(w0 - 1) * Ll + cA]);
    float qB = __expf(xbase[(w0 - 1) * Ll + cB]);
    float qC = __expf(xbase[(w0 - 1) * Ll + cC]);
    if (i < 32) { buf[cA] = qA; buf[cB] = qB; buf[cC] = qC; }
    asm volatile("" ::: "memory");
    PRELOAD

    float ewA = __expf(xbase[w0 * Ll + cA]);
    float ewB = __expf(xbase[w0 * Ll + cB]);
    float ewC = __expf(xbase[w0 * Ll + cC]);
#define ROWF(d) ((w0 + (d) > Tt - 1) ? (Tt - 1) : (w0 + (d)))
    float x2A = xbase[ROWF(1)*Ll+cA], x2B = xbase[ROWF(1)*Ll+cB], x2C = xbase[ROWF(1)*Ll+cC];
    float x3A = xbase[ROWF(2)*Ll+cA], x3B = xbase[ROWF(2)*Ll+cB], x3C = xbase[ROWF(2)*Ll+cC];
    float x4A = xbase[ROWF(3)*Ll+cA], x4B = xbase[ROWF(3)*Ll+cB], x4C = xbase[ROWF(3)*Ll+cC];
    float x5A = xbase[ROWF(4)*Ll+cA], x5B = xbase[ROWF(4)*Ll+cB], x5C = xbase[ROWF(4)*Ll+cC];
    float x6A = xbase[ROWF(5)*Ll+cA], x6B = xbase[ROWF(5)*Ll+cB], x6C = xbase[ROWF(5)*Ll+cC];
    float x7A = xbase[ROWF(6)*Ll+cA], x7B = xbase[ROWF(6)*Ll+cB], x7C = xbase[ROWF(6)*Ll+cC];
#undef ROWF

    int Dk = 0;
    float jsum = 1.f; int jdk = 0;      // junction capture
    #pragma unroll 1
    for (int t = w0; t < hi; ++t) {
        int k = ((__float_as_int(Pk) >> 23) & 0xff) - 127;  // wave-uniform
        Dk += k;
        float r = __uint_as_float((unsigned)(127 - k) << 23); // exact 2^-k
        float wA = ewA * r, wB = ewB * r, wC = ewC * r;

        v2f aA0 = {0.f,0.f}, aA1 = {0.f,0.f};
        v2f aB0 = {0.f,0.f}, aB1 = {0.f,0.f};
        v2f aC0 = {0.f,0.f}, aC1 = {0.f,0.f};
        MATVEC
        v2f tA = aA0 + aA1, tB = aB0 + aB1, tC = aC0 + aC1;
        qA = xadd32(tA.x + tA.y) * wA;
        qB = xadd32(tB.x + tB.y) * wB;
        qC = xadd32(tC.x + tC.y) * wC;

        if (i < 32) { buf[cA] = qA; buf[cB] = qB; buf[cC] = qC; }
        asm volatile("" ::: "memory");
        PRELOAD

        // junction capture (wave-uniform branch; taken once per chain)
        if (t == jt) {
            float ssum = qA + qB + qC;
            #pragma unroll
            for (int off = 16; off; off >>= 1) ssum += __shfl_xor(ssum, off, 64);
            jsum = ssum; jdk = Dk;
        }

        // off-path bookkeeping (overlaps the read-train latency)
        ewA = __expf(x2A); ewB = __expf(x2B); ewC = __expf(x2C);
        x2A = x3A; x2B = x3B; x2C = x3C;
        x3A = x4A; x3B = x4B; x3C = x4C;
        x4A = x5A; x4B = x5B; x4C = x5C;
        x5A = x6A; x5B = x6B; x5C = x6C;
        x6A = x7A; x6B = x7B; x6C = x7C;
        int row = t + 7; if (row > Tt - 1) row = Tt - 1;
        x7A = xbase[row*Ll+cA]; x7B = xbase[row*Ll+cB]; x7C = xbase[row*Ll+cC];
    }

    // end capture at t = hi-1
    float esum = qA + qB + qC;
    #pragma unroll
    for (int off = 16; off; off >>= 1) esum += __shfl_xor(esum, off, 64);

    if (i == 0) {
        wsb[s - 1]            = esum;
        wsb[NSEG + s - 1]     = jsum;
        wsi[2 * NSEG + s - 1] = Dk;
        wsi[3 * NSEG + s - 1] = jdk;
    }
#undef PRELOAD
#undef MATVEC
#undef CHUNK
#undef EP24
}

// logZ = sum_s [log(end_s) + ln2 DkEnd_s] - sum_{s>=2} [log(junc_s) + ln2 DkJunc_s]
__global__ __launch_bounds__(64, 1) void crf_combine_kernel(
    const float* __restrict__ ws, float* __restrict__ out)
{
    const int b = blockIdx.x;
    if (threadIdx.x != 0) return;
    const float* wsb = ws + (size_t)b * WS_STRIDE;
    const int*   wsi = reinterpret_cast<const int*>(wsb);
    const double LN2 = 0.6931471805599453;

    double acc = 0.0;
    #pragma unroll 1
    for (int s = 1; s <= NSEG; ++s) {
        acc += log((double)wsb[s - 1]) + LN2 * (double)wsi[2 * NSEG + s - 1];
        if (s >= 2)
            acc -= log((double)wsb[NSEG + s - 1]) + LN2 * (double)wsi[3 * NSEG + s - 1];
    }
    out[b] = (float)(acc - (double)wsb[4 * NSEG]);
}

extern "C" void kernel_launch(void* const* d_in, const int* in_sizes, int n_in,
                              void* d_out, int out_size, void* d_ws, size_t ws_size,
                              hipStream_t stream) {
    const float* inputs     = (const float*)d_in[0];
    const int*   labels_idx = (const int*)d_in[1];
    const float* trans      = (const float*)d_in[2];
    float*       out        = (float*)d_out;
    float*       ws         = (float*)d_ws;

    crf_scan_kernel<<<dim3((NSEG + 1) * Bb), dim3(64), 0, stream>>>(
        inputs, labels_idx, trans, ws);
    crf_combine_kernel<<<dim3(Bb), dim3(64), 0, stream>>>(ws, out);
}

// Round 22
// 135.579 us; speedup vs baseline: 1.1833x; 1.0039x over previous
//
#include <hip/hip_runtime.h>
#include <math.h>

#define Bb 128
#define Tt 1024
#define Ll 96
#define NSEG 16
#define DELTA 8
#define CUT(s) (1 + ((Tt - 1) * (s)) / NSEG)

// ws per batch: [0..N) end_sum (f32); [N..2N) junc_sum; [2N..3N) end_dk (i32);
// [3N..4N) junc_dk; [4N] ps.
#define WS_STRIDE 80

typedef float v2f __attribute__((ext_vector_type(2)));
typedef int   v2i __attribute__((ext_vector_type(2)));

// Cross-group (lane ^ 32) sum via v_permlane32_swap (VALU pipe, not LDS).
static __device__ __forceinline__ float xadd32(float p) {
#if __has_builtin(__builtin_amdgcn_permlane32_swap)
    v2i rr = __builtin_amdgcn_permlane32_swap(__float_as_int(p),
                                              __float_as_int(p), false, false);
    return __int_as_float(rr.x) + __int_as_float(rr.y);
#else
    return p + __shfl_xor(p, 32, 64);
#endif
}

// guaranteed packed fp32 (VOP3P); fma(a,b,0) == a*b exactly, so mul-first
// accumulator init is bit-identical to the += form.
#define PKFMA(d, a, b) asm("v_pk_fma_f32 %0, %1, %2, %0" : "+v"(d) : "v"(a), "v"(b));
#define PKMUL(d, a, b) asm("v_pk_mul_f32 %0, %1, %2"     : "=v"(d) : "v"(a), "v"(b));

// FORWARD-ONLY overlapped chains (R16/R19/R21 scheme).
// Round-22 = R20's instruction diet WITHOUT the unroll. R20 post-mortem:
// per-wave step time improved 0.57->0.39us (diet works) but the unroll-6
// body (~26KB) thrashed the CU I-cache across 8+ waves at different loop
// phases, and VGPR 152 crossed the >128 occupancy boundary -> concurrency
// collapse. This round keeps the ROLLED loop (~4KB body) + depth-6 queue
// with shifts, and applies only the per-wave diet:
//  1. ds_read_b64 pairs (clean v2f FMA operands, no repack movs)
//  2. asm v_pk_fma_f32 / v_pk_mul_f32 (72 packed FMAs, not 144 scalarized)
//  3. k via readfirstlane(Q0.x) (lane 0 holds state[0]; Dk on SALU)
// Accumulation order bit-identical to R21 -> absmax must stay 0.0.
__global__ __launch_bounds__(64, 1)
void crf_scan_kernel(
    const float* __restrict__ inputs,      // (B, T, L) fp32
    const int*   __restrict__ labels_idx,  // (B, T) int32
    const float* __restrict__ trans,       // (L, L) fp32
    float*       __restrict__ ws)          // 128 x WS_STRIDE floats
{
    const int cid = blockIdx.x / Bb;       // 0..NSEG-1 chains, NSEG = scores
    const int b   = blockIdx.x % Bb;
    const int i   = threadIdx.x;           // 0..63

    const float* xbase = inputs + (size_t)b * Tt * Ll;
    float* wsb = ws + (size_t)b * WS_STRIDE;
    int*   wsi = reinterpret_cast<int*>(wsb);

    if (cid == NSEG) {
        // ================= SCORES =================
        float ps = 0.f;
        const int* lb = labels_idx + b * Tt;
        #pragma unroll 4
        for (int t = i; t < Tt; t += 64) {
            int i0 = lb[t];
            ps += xbase[t * Ll + i0];
            if (t < Tt - 1) ps += trans[i0 * Ll + lb[t + 1]];
        }
        #pragma unroll
        for (int off = 32; off; off >>= 1) ps += __shfl_xor(ps, off, 64);
        if (i == 0) wsb[4 * NSEG] = ps;
        return;
    }

    const int s  = cid + 1;                          // 1..NSEG
    const int lo = CUT(s - 1), hi = CUT(s);          // segment [lo, hi)
    const int w0 = (s == 1) ? 1 : ((lo - DELTA < 1) ? 1 : lo - DELTA);
    const int jt = (s == 1) ? 0 : (lo - 1);          // junction t (0 = never)

    const int g   = i >> 5;            // group: state half [48g, 48g+48)
    const int j   = i & 31;            // slot: owns cols j, j+32, j+64
    const int g48 = g * 48;
    const int cA  = j, cB = j + 32, cC = j + 64;

    __shared__ __align__(16) float buf[Ll];

#define EP24(X) \
    X(0)  X(1)  X(2)  X(3)  X(4)  X(5)  X(6)  X(7)  X(8)  X(9)  X(10) X(11) \
    X(12) X(13) X(14) X(15) X(16) X(17) X(18) X(19) X(20) X(21) X(22) X(23)

#define EDECL(p) v2f EA##p, EB##p, EC##p;
    EP24(EDECL)
#undef EDECL
    // fwd layout: EA_p = {E[2p'][cA], E[2p'+1][cA]} for own-half elems
#define EINIT(p) { \
        int e0 = (g48 + 2*(p)) * Ll, e1 = (g48 + 2*(p) + 1) * Ll; \
        EA##p = (v2f){__expf(trans[e0 + cA]), __expf(trans[e1 + cA])}; \
        EB##p = (v2f){__expf(trans[e0 + cB]), __expf(trans[e1 + cB])}; \
        EC##p = (v2f){__expf(trans[e0 + cC]), __expf(trans[e1 + cC])}; \
        asm volatile("" ::: "memory"); }
    EP24(EINIT)
#undef EINIT

    // 24 x ds_read_b64: pair p = state elems {48g+2p, 48g+2p+1}, clean v2f.
#define QDECL(p) v2f Q##p;
    EP24(QDECL)
#undef QDECL
#define PRELOAD { const v2f* qb_ = reinterpret_cast<const v2f*>(buf) + g * 24; \
        Q0  = qb_[0];  Q1  = qb_[1];  Q2  = qb_[2];  Q3  = qb_[3];  \
        Q4  = qb_[4];  Q5  = qb_[5];  Q6  = qb_[6];  Q7  = qb_[7];  \
        Q8  = qb_[8];  Q9  = qb_[9];  Q10 = qb_[10]; Q11 = qb_[11]; \
        Q12 = qb_[12]; Q13 = qb_[13]; Q14 = qb_[14]; Q15 = qb_[15]; \
        Q16 = qb_[16]; Q17 = qb_[17]; Q18 = qb_[18]; Q19 = qb_[19]; \
        Q20 = qb_[20]; Q21 = qb_[21]; Q22 = qb_[22]; Q23 = qb_[23]; }

    // matvec: pair p feeds EA_p/EB_p/EC_p; even pairs -> acc0, odd -> acc1
    // (same grouping/order as R19/R21: bit-identical results).
#define MATVEC \
        v2f aA0, aA1, aB0, aB1, aC0, aC1; \
        PKMUL(aA0, Q0, EA0)  PKMUL(aB0, Q0, EB0)  PKMUL(aC0, Q0, EC0) \
        PKMUL(aA1, Q1, EA1)  PKMUL(aB1, Q1, EB1)  PKMUL(aC1, Q1, EC1) \
        PKFMA(aA0, Q2, EA2)  PKFMA(aB0, Q2, EB2)  PKFMA(aC0, Q2, EC2) \
        PKFMA(aA1, Q3, EA3)  PKFMA(aB1, Q3, EB3)  PKFMA(aC1, Q3, EC3) \
        PKFMA(aA0, Q4, EA4)  PKFMA(aB0, Q4, EB4)  PKFMA(aC0, Q4, EC4) \
        PKFMA(aA1, Q5, EA5)  PKFMA(aB1, Q5, EB5)  PKFMA(aC1, Q5, EC5) \
        PKFMA(aA0, Q6, EA6)  PKFMA(aB0, Q6, EB6)  PKFMA(aC0, Q6, EC6) \
        PKFMA(aA1, Q7, EA7)  PKFMA(aB1, Q7, EB7)  PKFMA(aC1, Q7, EC7) \
        PKFMA(aA0, Q8, EA8)  PKFMA(aB0, Q8, EB8)  PKFMA(aC0, Q8, EC8) \
        PKFMA(aA1, Q9, EA9)  PKFMA(aB1, Q9, EB9)  PKFMA(aC1, Q9, EC9) \
        PKFMA(aA0, Q10, EA10) PKFMA(aB0, Q10, EB10) PKFMA(aC0, Q10, EC10) \
        PKFMA(aA1, Q11, EA11) PKFMA(aB1, Q11, EB11) PKFMA(aC1, Q11, EC11) \
        PKFMA(aA0, Q12, EA12) PKFMA(aB0, Q12, EB12) PKFMA(aC0, Q12, EC12) \
        PKFMA(aA1, Q13, EA13) PKFMA(aB1, Q13, EB13) PKFMA(aC1, Q13, EC13) \
        PKFMA(aA0, Q14, EA14) PKFMA(aB0, Q14, EB14) PKFMA(aC0, Q14, EC14) \
        PKFMA(aA1, Q15, EA15) PKFMA(aB1, Q15, EB15) PKFMA(aC1, Q15, EC15) \
        PKFMA(aA0, Q16, EA16) PKFMA(aB0, Q16, EB16) PKFMA(aC0, Q16, EC16) \
        PKFMA(aA1, Q17, EA17) PKFMA(aB1, Q17, EB17) PKFMA(aC1, Q17, EC17) \
        PKFMA(aA0, Q18, EA18) PKFMA(aB0, Q18, EB18) PKFMA(aC0, Q18, EC18) \
        PKFMA(aA1, Q19, EA19) PKFMA(aB1, Q19, EB19) PKFMA(aC1, Q19, EC19) \
        PKFMA(aA0, Q20, EA20) PKFMA(aB0, Q20, EB20) PKFMA(aC0, Q20, EC20) \
        PKFMA(aA1, Q21, EA21) PKFMA(aB1, Q21, EB21) PKFMA(aC1, Q21, EC21) \
        PKFMA(aA0, Q22, EA22) PKFMA(aB0, Q22, EB22) PKFMA(aC0, Q22, EC22) \
        PKFMA(aA1, Q23, EA23) PKFMA(aB1, Q23, EB23) PKFMA(aC1, Q23, EC23)

    // ---- init state at t0 = w0-1: q = exp(x_{t0}) ----
    float qA = __expf(xbase[(w0 - 1) * Ll + cA]);
    float qB = __expf(xbase[(w0 - 1) * Ll + cB]);
    float qC = __expf(xbase[(w0 - 1) * Ll + cC]);
    if (i < 32) { buf[cA] = qA; buf[cB] = qB; buf[cC] = qC; }
    asm volatile("" ::: "memory");
    PRELOAD

    float ewA = __expf(xbase[w0 * Ll + cA]);
    float ewB = __expf(xbase[w0 * Ll + cB]);
    float ewC = __expf(xbase[w0 * Ll + cC]);
#define ROWF(d) ((w0 + (d) > Tt - 1) ? (Tt - 1) : (w0 + (d)))
    float x2A = xbase[ROWF(1)*Ll+cA], x2B = xbase[ROWF(1)*Ll+cB], x2C = xbase[ROWF(1)*Ll+cC];
    float x3A = xbase[ROWF(2)*Ll+cA], x3B = xbase[ROWF(2)*Ll+cB], x3C = xbase[ROWF(2)*Ll+cC];
    float x4A = xbase[ROWF(3)*Ll+cA], x4B = xbase[ROWF(3)*Ll+cB], x4C = xbase[ROWF(3)*Ll+cC];
    float x5A = xbase[ROWF(4)*Ll+cA], x5B = xbase[ROWF(4)*Ll+cB], x5C = xbase[ROWF(4)*Ll+cC];
    float x6A = xbase[ROWF(5)*Ll+cA], x6B = xbase[ROWF(5)*Ll+cB], x6C = xbase[ROWF(5)*Ll+cC];
    float x7A = xbase[ROWF(6)*Ll+cA], x7B = xbase[ROWF(6)*Ll+cB], x7C = xbase[ROWF(6)*Ll+cC];
#undef ROWF

    int Dk = 0;
    float jsum = 1.f; int jdk = 0;      // junction capture
    #pragma unroll 1
    for (int t = w0; t < hi; ++t) {
        // k from lane 0's Q0.x (= state[0], wave-uniform) via SALU
        int k = ((__builtin_amdgcn_readfirstlane(__float_as_int(Q0.x)) >> 23) & 0xff) - 127;
        Dk += k;
        float r = __uint_as_float((unsigned)(127 - k) << 23); // exact 2^-k
        float wA = ewA * r, wB = ewB * r, wC = ewC * r;

        MATVEC
        v2f tA = aA0 + aA1, tB = aB0 + aB1, tC = aC0 + aC1;
        qA = xadd32(tA.x + tA.y) * wA;
        qB = xadd32(tB.x + tB.y) * wB;
        qC = xadd32(tC.x + tC.y) * wC;

        if (i < 32) { buf[cA] = qA; buf[cB] = qB; buf[cC] = qC; }
        asm volatile("" ::: "memory");
        PRELOAD

        // junction capture (wave-uniform branch; taken once per chain)
        if (t == jt) {
            float ssum = qA + qB + qC;
            #pragma unroll
            for (int off = 16; off; off >>= 1) ssum += __shfl_xor(ssum, off, 64);
            jsum = ssum; jdk = Dk;
        }

        // off-path bookkeeping (overlaps the read-train latency)
        ewA = __expf(x2A); ewB = __expf(x2B); ewC = __expf(x2C);
        x2A = x3A; x2B = x3B; x2C = x3C;
        x3A = x4A; x3B = x4B; x3C = x4C;
        x4A = x5A; x4B = x5B; x4C = x5C;
        x5A = x6A; x5B = x6B; x5C = x6C;
        x6A = x7A; x6B = x7B; x6C = x7C;
        int row = t + 7; if (row > Tt - 1) row = Tt - 1;
        x7A = xbase[row*Ll+cA]; x7B = xbase[row*Ll+cB]; x7C = xbase[row*Ll+cC];
    }

    // end capture at t = hi-1
    float esum = qA + qB + qC;
    #pragma unroll
    for (int off = 16; off; off >>= 1) esum += __shfl_xor(esum, off, 64);

    if (i == 0) {
        wsb[s - 1]            = esum;
        wsb[NSEG + s - 1]     = jsum;
        wsi[2 * NSEG + s - 1] = Dk;
        wsi[3 * NSEG + s - 1] = jdk;
    }
#undef PRELOAD
#undef MATVEC
#undef EP24
}

// logZ = sum_s [log(end_s) + ln2 DkEnd_s] - sum_{s>=2} [log(junc_s) + ln2 DkJunc_s]
__global__ __launch_bounds__(64, 1) void crf_combine_kernel(
    const float* __restrict__ ws, float* __restrict__ out)
{
    const int b = blockIdx.x;
    if (threadIdx.x != 0) return;
    const float* wsb = ws + (size_t)b * WS_STRIDE;
    const int*   wsi = reinterpret_cast<const int*>(wsb);
    const double LN2 = 0.6931471805599453;

    double acc = 0.0;
    #pragma unroll 1
    for (int s = 1; s <= NSEG; ++s) {
        acc += log((double)wsb[s - 1]) + LN2 * (double)wsi[2 * NSEG + s - 1];
        if (s >= 2)
            acc -= log((double)wsb[NSEG + s - 1]) + LN2 * (double)wsi[3 * NSEG + s - 1];
    }
    out[b] = (float)(acc - (double)wsb[4 * NSEG]);
}

extern "C" void kernel_launch(void* const* d_in, const int* in_sizes, int n_in,
                              void* d_out, int out_size, void* d_ws, size_t ws_size,
                              hipStream_t stream) {
    const float* inputs     = (const float*)d_in[0];
    const int*   labels_idx = (const int*)d_in[1];
    const float* trans      = (const float*)d_in[2];
    float*       out        = (float*)d_out;
    float*       ws         = (float*)d_ws;

    crf_scan_kernel<<<dim3((NSEG + 1) * Bb), dim3(64), 0, stream>>>(
        inputs, labels_idx, trans, ws);
    crf_combine_kernel<<<dim3(Bb), dim3(64), 0, stream>>>(ws, out);
}